// Round 7
// baseline (3009.332 us; speedup 1.0000x reference)
//
#include <hip/hip_runtime.h>
#include <math.h>

#define S_LEN 4096
#define DMODEL 768
#define NHEAD 12
#define DHEAD 64
#define FFDIM 3072
#define NLAYER 12
#define WIN 256
#define QKVN 2304

typedef __bf16 bf16x8 __attribute__((ext_vector_type(8)));
typedef unsigned short u16x8 __attribute__((ext_vector_type(8)));
typedef float f32x4 __attribute__((ext_vector_type(4)));

// per-layer converted-weight block (ushorts): [WqkvT 3*dd][WoT dd][W1T df][W2T df]
#define WDD 589824       // 768*768
#define WDF 2359296      // 768*3072
#define WLAYER 7077888   // 3*WDD + WDD + 2*WDF

__device__ inline unsigned short f2bf(float f) {
    unsigned int u = __float_as_uint(f);
    u += 0x7fff + ((u >> 16) & 1);
    return (unsigned short)(u >> 16);
}

__device__ inline void gload16(const void* g, void* l) {
    __builtin_amdgcn_global_load_lds((const __attribute__((address_space(1))) void*)g,
                                     (__attribute__((address_space(3))) void*)l, 16, 0, 0);
}

// ---------------- LayerNorm ----------------

__device__ inline void block_reduce2(float& sum, float& sq) {
    #pragma unroll
    for (int off = 32; off; off >>= 1) {
        sum += __shfl_xor(sum, off);
        sq  += __shfl_xor(sq, off);
    }
    __shared__ float red[8];
    int wid = threadIdx.x >> 6, lane = threadIdx.x & 63;
    if (lane == 0) { red[wid] = sum; red[wid + 4] = sq; }
    __syncthreads();
    sum = red[0] + red[1] + red[2] + red[3];
    sq  = red[4] + red[5] + red[6] + red[7];
    __syncthreads();
}

__global__ __launch_bounds__(256) void ln_kernel(const float* __restrict__ in,
                                                 const float* __restrict__ s,
                                                 const float* __restrict__ b,
                                                 float* __restrict__ out,
                                                 unsigned short* __restrict__ outb) {
    int row = blockIdx.x, tid = threadIdx.x;
    const float* p = in + (size_t)row * DMODEL;
    float v0 = p[tid], v1 = p[tid + 256], v2 = p[tid + 512];
    float sum = v0 + v1 + v2;
    float sq  = v0 * v0 + v1 * v1 + v2 * v2;
    block_reduce2(sum, sq);
    float mu = sum * (1.0f / DMODEL);
    float var = sq * (1.0f / DMODEL) - mu * mu;
    float rs = rsqrtf(var + 1e-5f);
    float* o = out + (size_t)row * DMODEL;
    unsigned short* ob = outb + (size_t)row * DMODEL;
    float r0 = (v0 - mu) * rs * s[tid]       + b[tid];
    float r1 = (v1 - mu) * rs * s[tid + 256] + b[tid + 256];
    float r2 = (v2 - mu) * rs * s[tid + 512] + b[tid + 512];
    o[tid] = r0; o[tid + 256] = r1; o[tid + 512] = r2;
    ob[tid] = f2bf(r0); ob[tid + 256] = f2bf(r1); ob[tid + 512] = f2bf(r2);
}

__global__ __launch_bounds__(256) void embed_ln_kernel(const int* __restrict__ ids,
                                                       const float* __restrict__ wemb,
                                                       const float* __restrict__ pemb,
                                                       const float* __restrict__ s,
                                                       const float* __restrict__ b,
                                                       float* __restrict__ out,
                                                       unsigned short* __restrict__ outb) {
    int row = blockIdx.x, tid = threadIdx.x;
    int id = ids[row];
    const float* wp = wemb + (size_t)id * DMODEL;
    const float* pp = pemb + (size_t)(row + 2) * DMODEL;
    float v0 = wp[tid] + pp[tid];
    float v1 = wp[tid + 256] + pp[tid + 256];
    float v2 = wp[tid + 512] + pp[tid + 512];
    float sum = v0 + v1 + v2;
    float sq  = v0 * v0 + v1 * v1 + v2 * v2;
    block_reduce2(sum, sq);
    float mu = sum * (1.0f / DMODEL);
    float var = sq * (1.0f / DMODEL) - mu * mu;
    float rs = rsqrtf(var + 1e-5f);
    float* o = out + (size_t)row * DMODEL;
    unsigned short* ob = outb + (size_t)row * DMODEL;
    float r0 = (v0 - mu) * rs * s[tid]       + b[tid];
    float r1 = (v1 - mu) * rs * s[tid + 256] + b[tid + 256];
    float r2 = (v2 - mu) * rs * s[tid + 512] + b[tid + 512];
    o[tid] = r0; o[tid + 256] = r1; o[tid + 512] = r2;
    ob[tid] = f2bf(r0); ob[tid + 256] = f2bf(r1); ob[tid + 512] = f2bf(r2);
}

// ---------------- ALL-layers weight transpose + cvt (one dispatch) ----------------
// grid = 12 * 6912 blocks; layer = bid / 6912. Packed uint writes (2 bf16 / store).
__global__ __launch_bounds__(256) void transpose_all(const float* __restrict__ Wq,
                                                     const float* __restrict__ Wk,
                                                     const float* __restrict__ Wv,
                                                     const float* __restrict__ Wo,
                                                     const float* __restrict__ W1,
                                                     const float* __restrict__ W2,
                                                     unsigned short* __restrict__ wall) {
    const int l  = blockIdx.x / 6912;
    const int id = blockIdx.x % 6912;
    unsigned short* base = wall + (size_t)l * WLAYER;
    const float* src; unsigned short* dst; int C, R, bx, by;
    if (id < 2304) {
        const int m = id / 576, t2 = id % 576;
        src = ((m == 0) ? Wq : (m == 1) ? Wk : (m == 2) ? Wv : Wo) + (size_t)l * WDD;
        dst = base + (size_t)m * WDD;
        R = 768; C = 768; bx = (t2 % 24) * 32; by = (t2 / 24) * 32;
    } else if (id < 4608) {
        const int t2 = id - 2304;
        src = W1 + (size_t)l * WDF; dst = base + 4 * (size_t)WDD;
        R = 768; C = 3072; bx = (t2 % 96) * 32; by = (t2 / 96) * 32;
    } else {
        const int t2 = id - 4608;
        src = W2 + (size_t)l * WDF; dst = base + 4 * (size_t)WDD + WDF;
        R = 3072; C = 768; bx = (t2 % 24) * 32; by = (t2 / 24) * 32;
    }
    __shared__ float tile[32][33];
    const int tx = threadIdx.x & 31, ty = threadIdx.x >> 5;
    #pragma unroll
    for (int k = 0; k < 4; ++k)
        tile[ty + k * 8][tx] = src[(size_t)(by + ty + k * 8) * C + bx + tx];
    __syncthreads();
    const int c16 = threadIdx.x >> 4;   // 0..15
    const int rp  = threadIdx.x & 15;   // 0..15 (row pair)
    #pragma unroll
    for (int k = 0; k < 2; ++k) {
        const int c = c16 + k * 16;
        unsigned int lo = f2bf(tile[2 * rp][c]);
        unsigned int hi = f2bf(tile[2 * rp + 1][c]);
        *(unsigned int*)&dst[(size_t)(bx + c) * R + by + 2 * rp] = (hi << 16) | lo;
    }
}

__global__ __launch_bounds__(256) void bias_concat(const float* __restrict__ bq,
                                                   const float* __restrict__ bk,
                                                   const float* __restrict__ bv,
                                                   float* __restrict__ out) {
    int l = blockIdx.x, t = threadIdx.x;
    for (int i = t; i < DMODEL; i += 256) {
        out[(size_t)l * QKVN + i]              = bq[(size_t)l * DMODEL + i];
        out[(size_t)l * QKVN + DMODEL + i]     = bk[(size_t)l * DMODEL + i];
        out[(size_t)l * QKVN + 2 * DMODEL + i] = bv[(size_t)l * DMODEL + i];
    }
}

// ---------------- bf16 MFMA GEMM (runtime dims — R4-proven) ----------------
// C[M][N] = A[M][K] @ Bt[N][K]^T + bias (+res)(+gelu)
// MODE 0: fp32 out = acc+bias+res; 1: bf16 out = acc+bias; 2: bf16 out = gelu(acc+bias)
template<int MODE, int BN>
__global__ __launch_bounds__(256) void mfma_gemm(const unsigned short* __restrict__ A,
                                                 const unsigned short* __restrict__ Bt,
                                                 const float* __restrict__ bias,
                                                 const float* __restrict__ res,
                                                 void* __restrict__ Cout,
                                                 int M, int N, int K) {
    constexpr int MR = (BN == 128) ? 4 : 2;
    __shared__ unsigned short As[128 * 64];
    __shared__ unsigned short Bs[BN * 64];
    const int tid = threadIdx.x;
    const int wv = tid >> 6, lane = tid & 63;
    const int bm = blockIdx.x * 128, bn = blockIdx.y * BN;
    const int wr = (BN == 128) ? (wv >> 1) * 64 : wv * 32;
    const int wc = (BN == 128) ? (wv & 1) * 64 : 0;
    const int l15 = lane & 15, g = lane >> 4;

    f32x4 acc[MR][4];
    #pragma unroll
    for (int m = 0; m < MR; ++m)
        #pragma unroll
        for (int n = 0; n < 4; ++n)
            #pragma unroll
            for (int e = 0; e < 4; ++e) acc[m][n][e] = 0.f;

    const int srow = tid >> 3;
    const int scol = (tid & 7) * 8;

    for (int k0 = 0; k0 < K; k0 += 64) {
        __syncthreads();
        #pragma unroll
        for (int c = 0; c < 4; ++c)
            gload16(A + (size_t)(bm + c * 32 + srow) * K + k0 + scol,
                    (char*)As + c * 4096 + wv * 1024);
        #pragma unroll
        for (int c = 0; c < BN / 32; ++c)
            gload16(Bt + (size_t)(bn + c * 32 + srow) * K + k0 + scol,
                    (char*)Bs + c * 4096 + wv * 1024);
        __syncthreads();
        #pragma unroll
        for (int kk = 0; kk < 2; ++kk) {
            bf16x8 af[MR], bfr[4];
            #pragma unroll
            for (int m = 0; m < MR; ++m)
                af[m] = *(const bf16x8*)(As + (wr + m * 16 + l15) * 64 + kk * 32 + g * 8);
            #pragma unroll
            for (int n = 0; n < 4; ++n)
                bfr[n] = *(const bf16x8*)(Bs + (wc + n * 16 + l15) * 64 + kk * 32 + g * 8);
            #pragma unroll
            for (int m = 0; m < MR; ++m)
                #pragma unroll
                for (int n = 0; n < 4; ++n)
                    acc[m][n] = __builtin_amdgcn_mfma_f32_16x16x32_bf16(af[m], bfr[n], acc[m][n], 0, 0, 0);
        }
    }

    #pragma unroll
    for (int m = 0; m < MR; ++m) {
        const int row0 = bm + wr + m * 16 + g * 4;
        #pragma unroll
        for (int n = 0; n < 4; ++n) {
            const int col = bn + wc + n * 16 + l15;
            const float bb = bias[col];
            #pragma unroll
            for (int r = 0; r < 4; ++r) {
                float v = acc[m][n][r] + bb;
                if (MODE == 0) {
                    v += res[(size_t)(row0 + r) * N + col];
                    ((float*)Cout)[(size_t)(row0 + r) * N + col] = v;
                } else if (MODE == 1) {
                    ((unsigned short*)Cout)[(size_t)(row0 + r) * N + col] = f2bf(v);
                } else {
                    float gv = 0.5f * v * (1.0f + erff(v * 0.70710678118654752f));
                    ((unsigned short*)Cout)[(size_t)(row0 + r) * N + col] = f2bf(gv);
                }
            }
        }
    }
}

// ---------------- MFMA flash attention (sliding window) ----------------
// grid (S/64, H), block 256 = 4 waves, each wave owns 16 query rows. (R4-proven)
__global__ __launch_bounds__(256) void attn_mfma(const unsigned short* __restrict__ qkv,
                                                 const int* __restrict__ msk,
                                                 unsigned short* __restrict__ aout) {
    __shared__ unsigned short Ks[64 * 64];
    __shared__ unsigned short Vt[64 * 64];
    __shared__ unsigned short Ps[4][16 * 64];
    const int tid = threadIdx.x;
    const int wv = tid >> 6, lane = tid & 63;
    const int l15 = lane & 15, g = lane >> 4;
    const int h = blockIdx.y;
    const int q0 = blockIdx.x * 64;

    const int qrow = q0 + wv * 16 + l15;
    bf16x8 qf[2];
    #pragma unroll
    for (int kk = 0; kk < 2; ++kk)
        qf[kk] = *(const bf16x8*)(qkv + (size_t)qrow * QKVN + h * 64 + kk * 32 + g * 8);

    f32x4 o[4];
    #pragma unroll
    for (int n = 0; n < 4; ++n)
        #pragma unroll
        for (int e = 0; e < 4; ++e) o[n][e] = 0.f;
    float mst[4] = {-3e38f, -3e38f, -3e38f, -3e38f};
    float lst[4] = {0.f, 0.f, 0.f, 0.f};

    const int srow = tid >> 3;        // local key slot within 32-row chunk
    const int scol = (tid & 7) * 8;   // d offset (8 bf16)
    const int xr  = (l15 & 7) << 3;   // read-side XOR for K and P rows

    for (int c = 0; c < 9; ++c) {
        const int kc = q0 - 256 + c * 64;
        __syncthreads();
        // K: linear LDS dest, pre-swizzled global source column
        #pragma unroll
        for (int cc = 0; cc < 2; ++cc) {
            const int r = cc * 32 + srow;
            int krow = min(max(kc + r, 0), S_LEN - 1);
            gload16(qkv + (size_t)krow * QKVN + DMODEL + h * 64 + (scol ^ ((r & 7) << 3)),
                    (char*)Ks + cc * 4096 + wv * 1024);
        }
        // V: reg-staged transpose into swizzled Vt[d][key ^ f(d)]
        #pragma unroll
        for (int cc = 0; cc < 2; ++cc) {
            const int r = cc * 32 + srow;
            int vrow = min(max(kc + r, 0), S_LEN - 1);
            u16x8 vvv = *(const u16x8*)(qkv + (size_t)vrow * QKVN + 2 * DMODEL + h * 64 + scol);
            const int xb = (scol >> 3) & 7;
            #pragma unroll
            for (int j = 0; j < 8; ++j)
                Vt[(scol + j) * 64 + (r ^ ((xb ^ j) << 3))] = vvv[j];
        }
        __syncthreads();

        // S = Q K^T
        f32x4 s[4];
        #pragma unroll
        for (int n = 0; n < 4; ++n)
            #pragma unroll
            for (int e = 0; e < 4; ++e) s[n][e] = 0.f;
        #pragma unroll
        for (int kk = 0; kk < 2; ++kk) {
            #pragma unroll
            for (int n = 0; n < 4; ++n) {
                bf16x8 kf = *(const bf16x8*)(Ks + (n * 16 + l15) * 64 + ((kk * 32 + g * 8) ^ xr));
                s[n] = __builtin_amdgcn_mfma_f32_16x16x32_bf16(qf[kk], kf, s[n], 0, 0, 0);
            }
        }

        // mask + online softmax
        float pv[4][4];
        const int qbase = q0 + wv * 16 + g * 4;
        #pragma unroll
        for (int n = 0; n < 4; ++n) {
            const int key = kc + n * 16 + l15;
            const bool kin = (key >= 0) && (key < S_LEN);
            const int mv = kin ? msk[key] : 0;
            #pragma unroll
            for (int r = 0; r < 4; ++r) {
                const int qa = qbase + r;
                const bool valid = (mv != 0) && (abs(key - qa) <= WIN);
                pv[n][r] = valid ? s[n][r] * 0.125f : -1e9f;
            }
        }
        float scold[4];
        #pragma unroll
        for (int r = 0; r < 4; ++r) {
            float mx = fmaxf(fmaxf(pv[0][r], pv[1][r]), fmaxf(pv[2][r], pv[3][r]));
            mx = fmaxf(mx, __shfl_xor(mx, 1));
            mx = fmaxf(mx, __shfl_xor(mx, 2));
            mx = fmaxf(mx, __shfl_xor(mx, 4));
            mx = fmaxf(mx, __shfl_xor(mx, 8));
            const float nm = fmaxf(mst[r], mx);
            scold[r] = expf(mst[r] - nm);
            float sum = 0.f;
            #pragma unroll
            for (int n = 0; n < 4; ++n) { pv[n][r] = expf(pv[n][r] - nm); sum += pv[n][r]; }
            sum += __shfl_xor(sum, 1); sum += __shfl_xor(sum, 2);
            sum += __shfl_xor(sum, 4); sum += __shfl_xor(sum, 8);
            lst[r] = lst[r] * scold[r] + sum;
            mst[r] = nm;
        }
        #pragma unroll
        for (int n = 0; n < 4; ++n)
            #pragma unroll
            for (int r = 0; r < 4; ++r)
                o[n][r] *= scold[r];

        // P -> LDS (swizzled by local q row)
        #pragma unroll
        for (int n = 0; n < 4; ++n)
            #pragma unroll
            for (int r = 0; r < 4; ++r) {
                const int ql = g * 4 + r;
                Ps[wv][ql * 64 + ((n * 16 + l15) ^ ((ql & 7) << 3))] = f2bf(pv[n][r]);
            }

        // O += P @ V
        #pragma unroll
        for (int kk = 0; kk < 2; ++kk) {
            bf16x8 pf = *(const bf16x8*)(Ps[wv] + l15 * 64 + ((kk * 32 + g * 8) ^ xr));
            #pragma unroll
            for (int nd = 0; nd < 4; ++nd) {
                const int d = nd * 16 + l15;
                const int xv = (((nd * 2 + (l15 >> 3)) & 7) ^ (l15 & 7)) << 3;
                bf16x8 vf = *(const bf16x8*)(Vt + d * 64 + ((kk * 32 + g * 8) ^ xv));
                o[nd] = __builtin_amdgcn_mfma_f32_16x16x32_bf16(pf, vf, o[nd], 0, 0, 0);
            }
        }
    }

    #pragma unroll
    for (int r = 0; r < 4; ++r) {
        const float inv = 1.0f / lst[r];
        const int qa = q0 + wv * 16 + g * 4 + r;
        #pragma unroll
        for (int nd = 0; nd < 4; ++nd)
            aout[(size_t)qa * DMODEL + h * 64 + nd * 16 + l15] = f2bf(o[nd][r] * inv);
    }
}

// ---------------- Head MLP (parallelized) ----------------
__global__ __launch_bounds__(256) void head1_kernel(const int* __restrict__ ids,
                                                    const float* __restrict__ x,
                                                    const float* __restrict__ w1,
                                                    const float* __restrict__ b1,
                                                    float* __restrict__ z1) {
    const int tid = threadIdx.x;
    __shared__ int sred[256];
    int loc = -1;
    for (int i = tid; i < S_LEN; i += 256)
        if (ids[i] == 2) loc = i;
    sred[tid] = loc;
    __syncthreads();
    for (int s2 = 128; s2; s2 >>= 1) {
        if (tid < s2) sred[tid] = max(sred[tid], sred[tid + s2]);
        __syncthreads();
    }
    const int sep = sred[0] < 0 ? (S_LEN - 1) : sred[0];

    __shared__ float emb[DMODEL];
    for (int d = tid; d < DMODEL; d += 256) emb[d] = x[(size_t)sep * DMODEL + d];
    __syncthreads();

    const int o = blockIdx.x * 64 + (tid & 63);
    const int chunk = tid >> 6;
    float s = 0.f;
    const int d0 = chunk * 192;
    for (int d = d0; d < d0 + 192; ++d)
        s += emb[d] * w1[(size_t)d * 512 + o];
    __shared__ float part[4][64];
    part[chunk][tid & 63] = s;
    __syncthreads();
    if (chunk == 0) {
        float v = part[0][tid] + part[1][tid] + part[2][tid] + part[3][tid] + b1[o];
        z1[o] = fmaxf(v, 0.f);
    }
}

__global__ __launch_bounds__(256) void head2_kernel(const float* __restrict__ z1,
                                                    const float* __restrict__ w2,
                                                    const float* __restrict__ b2,
                                                    const float* __restrict__ w3,
                                                    const float* __restrict__ b3,
                                                    float* __restrict__ out) {
    const int tid = threadIdx.x;
    __shared__ float z1s[512];
    for (int i = tid; i < 512; i += 256) z1s[i] = z1[i];
    __syncthreads();
    float s = b2[tid];
    for (int d = 0; d < 512; ++d) s += z1s[d] * w2[(size_t)d * 256 + tid];
    float z2 = fmaxf(s, 0.f);
    __shared__ float fred[256];
    fred[tid] = z2 * w3[tid];
    __syncthreads();
    for (int s2 = 128; s2; s2 >>= 1) {
        if (tid < s2) fred[tid] += fred[tid + s2];
        __syncthreads();
    }
    if (tid == 0) out[0] = tanhf(fred[0] + b3[0]);
}

// ---------------- launch ----------------

extern "C" void kernel_launch(void* const* d_in, const int* in_sizes, int n_in,
                              void* d_out, int out_size, void* d_ws, size_t ws_size,
                              hipStream_t stream) {
    const int*   ids      = (const int*)d_in[0];
    const int*   amask    = (const int*)d_in[1];
    const float* word_emb = (const float*)d_in[2];
    const float* pos_emb  = (const float*)d_in[3];
    const float* emb_s    = (const float*)d_in[4];
    const float* emb_b    = (const float*)d_in[5];
    const float* Wq = (const float*)d_in[6];
    const float* bq = (const float*)d_in[7];
    const float* Wk = (const float*)d_in[8];
    const float* bk = (const float*)d_in[9];
    const float* Wv = (const float*)d_in[10];
    const float* bv = (const float*)d_in[11];
    const float* Wo = (const float*)d_in[12];
    const float* bo = (const float*)d_in[13];
    const float* l1s = (const float*)d_in[14];
    const float* l1b = (const float*)d_in[15];
    const float* W1 = (const float*)d_in[16];
    const float* b1 = (const float*)d_in[17];
    const float* W2 = (const float*)d_in[18];
    const float* b2 = (const float*)d_in[19];
    const float* l2s = (const float*)d_in[20];
    const float* l2b = (const float*)d_in[21];
    const float* h1w = (const float*)d_in[22];
    const float* h1b = (const float*)d_in[23];
    const float* h2w = (const float*)d_in[24];
    const float* h2b = (const float*)d_in[25];
    const float* h3w = (const float*)d_in[26];
    const float* h3b = (const float*)d_in[27];

    char* ws = (char*)d_ws;
    float* x          = (float*)(ws);                              // 12.58 MB
    float* t          = (float*)(ws + 12582912);                   // 12.58 MB
    unsigned short* xb   = (unsigned short*)(ws + 25165824);       // 6.29 MB
    unsigned short* qkv  = (unsigned short*)(ws + 31457280);       // 18.87 MB
    unsigned short* a    = (unsigned short*)(ws + 50331648);       // 6.29 MB
    unsigned short* hb   = (unsigned short*)(ws + 56623104);       // 25.17 MB
    float* biascat       = (float*)(ws + 81788928);                // 0.11 MB
    float* z1ws          = (float*)(ws + 81920000);                // 2 KB
    unsigned short* wall = (unsigned short*)(ws + 100663296);      // 162 MB (12 layers)

    bias_concat<<<NLAYER, 256, 0, stream>>>(bq, bk, bv, biascat);
    transpose_all<<<6912 * NLAYER, 256, 0, stream>>>(Wq, Wk, Wv, Wo, W1, W2, wall);
    embed_ln_kernel<<<S_LEN, 256, 0, stream>>>(ids, word_emb, pos_emb, emb_s, emb_b, x, xb);

    for (int l = 0; l < NLAYER; ++l) {
        const unsigned short* WqkvT = wall + (size_t)l * WLAYER;
        const unsigned short* WoT   = WqkvT + 3 * (size_t)WDD;
        const unsigned short* W1T   = WqkvT + 4 * (size_t)WDD;
        const unsigned short* W2T   = WqkvT + 4 * (size_t)WDD + WDF;

        mfma_gemm<1, 128><<<dim3(32, 18), 256, 0, stream>>>(xb, WqkvT, biascat + (size_t)l * QKVN,
                                                            nullptr, qkv, S_LEN, QKVN, DMODEL);
        attn_mfma<<<dim3(S_LEN / 64, NHEAD), 256, 0, stream>>>(qkv, amask, a);

        mfma_gemm<0, 64><<<dim3(32, 12), 256, 0, stream>>>(a, WoT, bo + (size_t)l * DMODEL,
                                                           x, t, S_LEN, DMODEL, DMODEL);
        ln_kernel<<<S_LEN, 256, 0, stream>>>(t, l1s + (size_t)l * DMODEL, l1b + (size_t)l * DMODEL, x, xb);

        mfma_gemm<2, 128><<<dim3(32, 24), 256, 0, stream>>>(xb, W1T, b1 + (size_t)l * FFDIM,
                                                            nullptr, hb, S_LEN, FFDIM, DMODEL);
        mfma_gemm<0, 64><<<dim3(32, 12), 256, 0, stream>>>(hb, W2T, b2 + (size_t)l * DMODEL,
                                                           x, t, S_LEN, DMODEL, FFDIM);
        ln_kernel<<<S_LEN, 256, 0, stream>>>(t, l2s + (size_t)l * DMODEL, l2b + (size_t)l * DMODEL, x, xb);
    }

    head1_kernel<<<8, 256, 0, stream>>>(ids, x, h1w, h1b, z1ws);
    head2_kernel<<<1, 256, 0, stream>>>(z1ws, h2w, h2b, h3w, h3b, (float*)d_out);
}

// Round 8
// 2746.247 us; speedup vs baseline: 1.0958x; 1.0958x over previous
//
#include <hip/hip_runtime.h>
#include <math.h>

#define S_LEN 4096
#define DMODEL 768
#define NHEAD 12
#define DHEAD 64
#define FFDIM 3072
#define NLAYER 12
#define WIN 256
#define QKVN 2304

typedef __bf16 bf16x8 __attribute__((ext_vector_type(8)));
typedef unsigned short u16x8 __attribute__((ext_vector_type(8)));
typedef float f32x4 __attribute__((ext_vector_type(4)));

__device__ inline unsigned short f2bf(float f) {
    unsigned int u = __float_as_uint(f);
    u += 0x7fff + ((u >> 16) & 1);
    return (unsigned short)(u >> 16);
}

__device__ inline void gload16(const void* g, void* l) {
    __builtin_amdgcn_global_load_lds((const __attribute__((address_space(1))) void*)g,
                                     (__attribute__((address_space(3))) void*)l, 16, 0, 0);
}

// ---------------- LayerNorm ----------------

__device__ inline void block_reduce2(float& sum, float& sq) {
    #pragma unroll
    for (int off = 32; off; off >>= 1) {
        sum += __shfl_xor(sum, off);
        sq  += __shfl_xor(sq, off);
    }
    __shared__ float red[8];
    int wid = threadIdx.x >> 6, lane = threadIdx.x & 63;
    if (lane == 0) { red[wid] = sum; red[wid + 4] = sq; }
    __syncthreads();
    sum = red[0] + red[1] + red[2] + red[3];
    sq  = red[4] + red[5] + red[6] + red[7];
    __syncthreads();
}

__global__ __launch_bounds__(256) void ln_kernel(const float* __restrict__ in,
                                                 const float* __restrict__ s,
                                                 const float* __restrict__ b,
                                                 float* __restrict__ out,
                                                 unsigned short* __restrict__ outb) {
    int row = blockIdx.x, tid = threadIdx.x;
    const float* p = in + (size_t)row * DMODEL;
    float v0 = p[tid], v1 = p[tid + 256], v2 = p[tid + 512];
    float sum = v0 + v1 + v2;
    float sq  = v0 * v0 + v1 * v1 + v2 * v2;
    block_reduce2(sum, sq);
    float mu = sum * (1.0f / DMODEL);
    float var = sq * (1.0f / DMODEL) - mu * mu;
    float rs = rsqrtf(var + 1e-5f);
    float* o = out + (size_t)row * DMODEL;
    unsigned short* ob = outb + (size_t)row * DMODEL;
    float r0 = (v0 - mu) * rs * s[tid]       + b[tid];
    float r1 = (v1 - mu) * rs * s[tid + 256] + b[tid + 256];
    float r2 = (v2 - mu) * rs * s[tid + 512] + b[tid + 512];
    o[tid] = r0; o[tid + 256] = r1; o[tid + 512] = r2;
    ob[tid] = f2bf(r0); ob[tid + 256] = f2bf(r1); ob[tid + 512] = f2bf(r2);
}

__global__ __launch_bounds__(256) void embed_ln_kernel(const int* __restrict__ ids,
                                                       const float* __restrict__ wemb,
                                                       const float* __restrict__ pemb,
                                                       const float* __restrict__ s,
                                                       const float* __restrict__ b,
                                                       float* __restrict__ out,
                                                       unsigned short* __restrict__ outb) {
    int row = blockIdx.x, tid = threadIdx.x;
    int id = ids[row];
    const float* wp = wemb + (size_t)id * DMODEL;
    const float* pp = pemb + (size_t)(row + 2) * DMODEL;
    float v0 = wp[tid] + pp[tid];
    float v1 = wp[tid + 256] + pp[tid + 256];
    float v2 = wp[tid + 512] + pp[tid + 512];
    float sum = v0 + v1 + v2;
    float sq  = v0 * v0 + v1 * v1 + v2 * v2;
    block_reduce2(sum, sq);
    float mu = sum * (1.0f / DMODEL);
    float var = sq * (1.0f / DMODEL) - mu * mu;
    float rs = rsqrtf(var + 1e-5f);
    float* o = out + (size_t)row * DMODEL;
    unsigned short* ob = outb + (size_t)row * DMODEL;
    float r0 = (v0 - mu) * rs * s[tid]       + b[tid];
    float r1 = (v1 - mu) * rs * s[tid + 256] + b[tid + 256];
    float r2 = (v2 - mu) * rs * s[tid + 512] + b[tid + 512];
    o[tid] = r0; o[tid + 256] = r1; o[tid + 512] = r2;
    ob[tid] = f2bf(r0); ob[tid + 256] = f2bf(r1); ob[tid + 512] = f2bf(r2);
}

// ---------------- merged per-layer weight transpose + cvt ----------------
// One dispatch converts all 6 weight matrices of a layer (R4-proven).
__global__ __launch_bounds__(256) void transpose_all(const float* __restrict__ wq,
                                                     const float* __restrict__ wk,
                                                     const float* __restrict__ wv,
                                                     const float* __restrict__ wo,
                                                     const float* __restrict__ w1,
                                                     const float* __restrict__ w2,
                                                     unsigned short* __restrict__ dq,
                                                     unsigned short* __restrict__ dk,
                                                     unsigned short* __restrict__ dv,
                                                     unsigned short* __restrict__ dwo,
                                                     unsigned short* __restrict__ d1,
                                                     unsigned short* __restrict__ d2) {
    const int id = blockIdx.x;
    const float* src; unsigned short* dst; int C, R, bx, by;
    if (id < 2304) {
        const int m = id / 576, t2 = id % 576;
        src = (m == 0) ? wq : (m == 1) ? wk : (m == 2) ? wv : wo;
        dst = (m == 0) ? dq : (m == 1) ? dk : (m == 2) ? dv : dwo;
        R = 768; C = 768; bx = (t2 % 24) * 32; by = (t2 / 24) * 32;
    } else if (id < 4608) {
        const int t2 = id - 2304;
        src = w1; dst = d1; R = 768; C = 3072;
        bx = (t2 % 96) * 32; by = (t2 / 96) * 32;
    } else {
        const int t2 = id - 4608;
        src = w2; dst = d2; R = 3072; C = 768;
        bx = (t2 % 24) * 32; by = (t2 / 24) * 32;
    }
    __shared__ float tile[32][33];
    const int tx = threadIdx.x & 31, ty = threadIdx.x >> 5;
    #pragma unroll
    for (int k = 0; k < 4; ++k)
        tile[ty + k * 8][tx] = src[(size_t)(by + ty + k * 8) * C + bx + tx];
    __syncthreads();
    #pragma unroll
    for (int k = 0; k < 4; ++k)
        dst[(size_t)(bx + ty + k * 8) * R + by + tx] = f2bf(tile[tx][ty + k * 8]);
}

__global__ __launch_bounds__(256) void bias_concat(const float* __restrict__ bq,
                                                   const float* __restrict__ bk,
                                                   const float* __restrict__ bv,
                                                   float* __restrict__ out) {
    int l = blockIdx.x, t = threadIdx.x;
    for (int i = t; i < DMODEL; i += 256) {
        out[(size_t)l * QKVN + i]              = bq[(size_t)l * DMODEL + i];
        out[(size_t)l * QKVN + DMODEL + i]     = bk[(size_t)l * DMODEL + i];
        out[(size_t)l * QKVN + 2 * DMODEL + i] = bv[(size_t)l * DMODEL + i];
    }
}

// ---------------- bf16 MFMA GEMM (runtime dims — R4-proven) ----------------
// C[M][N] = A[M][K] @ Bt[N][K]^T + bias (+res)(+gelu)
// MODE 0: fp32 out = acc+bias+res; 1: bf16 out = acc+bias; 2: bf16 out = gelu(acc+bias)
template<int MODE, int BN>
__global__ __launch_bounds__(256) void mfma_gemm(const unsigned short* __restrict__ A,
                                                 const unsigned short* __restrict__ Bt,
                                                 const float* __restrict__ bias,
                                                 const float* __restrict__ res,
                                                 void* __restrict__ Cout,
                                                 int M, int N, int K) {
    constexpr int MR = (BN == 128) ? 4 : 2;
    __shared__ unsigned short As[128 * 64];
    __shared__ unsigned short Bs[BN * 64];
    const int tid = threadIdx.x;
    const int wv = tid >> 6, lane = tid & 63;
    const int bm = blockIdx.x * 128, bn = blockIdx.y * BN;
    const int wr = (BN == 128) ? (wv >> 1) * 64 : wv * 32;
    const int wc = (BN == 128) ? (wv & 1) * 64 : 0;
    const int l15 = lane & 15, g = lane >> 4;

    f32x4 acc[MR][4];
    #pragma unroll
    for (int m = 0; m < MR; ++m)
        #pragma unroll
        for (int n = 0; n < 4; ++n)
            #pragma unroll
            for (int e = 0; e < 4; ++e) acc[m][n][e] = 0.f;

    const int srow = tid >> 3;
    const int scol = (tid & 7) * 8;

    for (int k0 = 0; k0 < K; k0 += 64) {
        __syncthreads();
        #pragma unroll
        for (int c = 0; c < 4; ++c)
            gload16(A + (size_t)(bm + c * 32 + srow) * K + k0 + scol,
                    (char*)As + c * 4096 + wv * 1024);
        #pragma unroll
        for (int c = 0; c < BN / 32; ++c)
            gload16(Bt + (size_t)(bn + c * 32 + srow) * K + k0 + scol,
                    (char*)Bs + c * 4096 + wv * 1024);
        __syncthreads();
        #pragma unroll
        for (int kk = 0; kk < 2; ++kk) {
            bf16x8 af[MR], bfr[4];
            #pragma unroll
            for (int m = 0; m < MR; ++m)
                af[m] = *(const bf16x8*)(As + (wr + m * 16 + l15) * 64 + kk * 32 + g * 8);
            #pragma unroll
            for (int n = 0; n < 4; ++n)
                bfr[n] = *(const bf16x8*)(Bs + (wc + n * 16 + l15) * 64 + kk * 32 + g * 8);
            #pragma unroll
            for (int m = 0; m < MR; ++m)
                #pragma unroll
                for (int n = 0; n < 4; ++n)
                    acc[m][n] = __builtin_amdgcn_mfma_f32_16x16x32_bf16(af[m], bfr[n], acc[m][n], 0, 0, 0);
        }
    }

    #pragma unroll
    for (int m = 0; m < MR; ++m) {
        const int row0 = bm + wr + m * 16 + g * 4;
        #pragma unroll
        for (int n = 0; n < 4; ++n) {
            const int col = bn + wc + n * 16 + l15;
            const float bb = bias[col];
            #pragma unroll
            for (int r = 0; r < 4; ++r) {
                float v = acc[m][n][r] + bb;
                if (MODE == 0) {
                    v += res[(size_t)(row0 + r) * N + col];
                    ((float*)Cout)[(size_t)(row0 + r) * N + col] = v;
                } else if (MODE == 1) {
                    ((unsigned short*)Cout)[(size_t)(row0 + r) * N + col] = f2bf(v);
                } else {
                    float gv = 0.5f * v * (1.0f + erff(v * 0.70710678118654752f));
                    ((unsigned short*)Cout)[(size_t)(row0 + r) * N + col] = f2bf(gv);
                }
            }
        }
    }
}

// ---------------- MFMA flash attention (sliding window) ----------------
// grid (S/64, H), block 256 = 4 waves, each wave owns 16 query rows. (R4-proven)
__global__ __launch_bounds__(256) void attn_mfma(const unsigned short* __restrict__ qkv,
                                                 const int* __restrict__ msk,
                                                 unsigned short* __restrict__ aout) {
    __shared__ unsigned short Ks[64 * 64];
    __shared__ unsigned short Vt[64 * 64];
    __shared__ unsigned short Ps[4][16 * 64];
    const int tid = threadIdx.x;
    const int wv = tid >> 6, lane = tid & 63;
    const int l15 = lane & 15, g = lane >> 4;
    const int h = blockIdx.y;
    const int q0 = blockIdx.x * 64;

    const int qrow = q0 + wv * 16 + l15;
    bf16x8 qf[2];
    #pragma unroll
    for (int kk = 0; kk < 2; ++kk)
        qf[kk] = *(const bf16x8*)(qkv + (size_t)qrow * QKVN + h * 64 + kk * 32 + g * 8);

    f32x4 o[4];
    #pragma unroll
    for (int n = 0; n < 4; ++n)
        #pragma unroll
        for (int e = 0; e < 4; ++e) o[n][e] = 0.f;
    float mst[4] = {-3e38f, -3e38f, -3e38f, -3e38f};
    float lst[4] = {0.f, 0.f, 0.f, 0.f};

    const int srow = tid >> 3;        // local key slot within 32-row chunk
    const int scol = (tid & 7) * 8;   // d offset (8 bf16)
    const int xr  = (l15 & 7) << 3;   // read-side XOR for K and P rows

    for (int c = 0; c < 9; ++c) {
        const int kc = q0 - 256 + c * 64;
        __syncthreads();
        // K: linear LDS dest, pre-swizzled global source column
        #pragma unroll
        for (int cc = 0; cc < 2; ++cc) {
            const int r = cc * 32 + srow;
            int krow = min(max(kc + r, 0), S_LEN - 1);
            gload16(qkv + (size_t)krow * QKVN + DMODEL + h * 64 + (scol ^ ((r & 7) << 3)),
                    (char*)Ks + cc * 4096 + wv * 1024);
        }
        // V: reg-staged transpose into swizzled Vt[d][key ^ f(d)]
        #pragma unroll
        for (int cc = 0; cc < 2; ++cc) {
            const int r = cc * 32 + srow;
            int vrow = min(max(kc + r, 0), S_LEN - 1);
            u16x8 vvv = *(const u16x8*)(qkv + (size_t)vrow * QKVN + 2 * DMODEL + h * 64 + scol);
            const int xb = (scol >> 3) & 7;
            #pragma unroll
            for (int j = 0; j < 8; ++j)
                Vt[(scol + j) * 64 + (r ^ ((xb ^ j) << 3))] = vvv[j];
        }
        __syncthreads();

        // S = Q K^T
        f32x4 s[4];
        #pragma unroll
        for (int n = 0; n < 4; ++n)
            #pragma unroll
            for (int e = 0; e < 4; ++e) s[n][e] = 0.f;
        #pragma unroll
        for (int kk = 0; kk < 2; ++kk) {
            #pragma unroll
            for (int n = 0; n < 4; ++n) {
                bf16x8 kf = *(const bf16x8*)(Ks + (n * 16 + l15) * 64 + ((kk * 32 + g * 8) ^ xr));
                s[n] = __builtin_amdgcn_mfma_f32_16x16x32_bf16(qf[kk], kf, s[n], 0, 0, 0);
            }
        }

        // mask + online softmax
        float pv[4][4];
        const int qbase = q0 + wv * 16 + g * 4;
        #pragma unroll
        for (int n = 0; n < 4; ++n) {
            const int key = kc + n * 16 + l15;
            const bool kin = (key >= 0) && (key < S_LEN);
            const int mv = kin ? msk[key] : 0;
            #pragma unroll
            for (int r = 0; r < 4; ++r) {
                const int qa = qbase + r;
                const bool valid = (mv != 0) && (abs(key - qa) <= WIN);
                pv[n][r] = valid ? s[n][r] * 0.125f : -1e9f;
            }
        }
        float scold[4];
        #pragma unroll
        for (int r = 0; r < 4; ++r) {
            float mx = fmaxf(fmaxf(pv[0][r], pv[1][r]), fmaxf(pv[2][r], pv[3][r]));
            mx = fmaxf(mx, __shfl_xor(mx, 1));
            mx = fmaxf(mx, __shfl_xor(mx, 2));
            mx = fmaxf(mx, __shfl_xor(mx, 4));
            mx = fmaxf(mx, __shfl_xor(mx, 8));
            const float nm = fmaxf(mst[r], mx);
            scold[r] = expf(mst[r] - nm);
            float sum = 0.f;
            #pragma unroll
            for (int n = 0; n < 4; ++n) { pv[n][r] = expf(pv[n][r] - nm); sum += pv[n][r]; }
            sum += __shfl_xor(sum, 1); sum += __shfl_xor(sum, 2);
            sum += __shfl_xor(sum, 4); sum += __shfl_xor(sum, 8);
            lst[r] = lst[r] * scold[r] + sum;
            mst[r] = nm;
        }
        #pragma unroll
        for (int n = 0; n < 4; ++n)
            #pragma unroll
            for (int r = 0; r < 4; ++r)
                o[n][r] *= scold[r];

        // P -> LDS (swizzled by local q row)
        #pragma unroll
        for (int n = 0; n < 4; ++n)
            #pragma unroll
            for (int r = 0; r < 4; ++r) {
                const int ql = g * 4 + r;
                Ps[wv][ql * 64 + ((n * 16 + l15) ^ ((ql & 7) << 3))] = f2bf(pv[n][r]);
            }

        // O += P @ V
        #pragma unroll
        for (int kk = 0; kk < 2; ++kk) {
            bf16x8 pf = *(const bf16x8*)(Ps[wv] + l15 * 64 + ((kk * 32 + g * 8) ^ xr));
            #pragma unroll
            for (int nd = 0; nd < 4; ++nd) {
                const int d = nd * 16 + l15;
                const int xv = (((nd * 2 + (l15 >> 3)) & 7) ^ (l15 & 7)) << 3;
                bf16x8 vf = *(const bf16x8*)(Vt + d * 64 + ((kk * 32 + g * 8) ^ xv));
                o[nd] = __builtin_amdgcn_mfma_f32_16x16x32_bf16(pf, vf, o[nd], 0, 0, 0);
            }
        }
    }

    #pragma unroll
    for (int r = 0; r < 4; ++r) {
        const float inv = 1.0f / lst[r];
        const int qa = q0 + wv * 16 + g * 4 + r;
        #pragma unroll
        for (int nd = 0; nd < 4; ++nd)
            aout[(size_t)qa * DMODEL + h * 64 + nd * 16 + l15] = f2bf(o[nd][r] * inv);
    }
}

// ---------------- Head MLP (parallelized) ----------------
__global__ __launch_bounds__(256) void head1_kernel(const int* __restrict__ ids,
                                                    const float* __restrict__ x,
                                                    const float* __restrict__ w1,
                                                    const float* __restrict__ b1,
                                                    float* __restrict__ z1) {
    const int tid = threadIdx.x;
    __shared__ int sred[256];
    int loc = -1;
    for (int i = tid; i < S_LEN; i += 256)
        if (ids[i] == 2) loc = i;
    sred[tid] = loc;
    __syncthreads();
    for (int s2 = 128; s2; s2 >>= 1) {
        if (tid < s2) sred[tid] = max(sred[tid], sred[tid + s2]);
        __syncthreads();
    }
    const int sep = sred[0] < 0 ? (S_LEN - 1) : sred[0];

    __shared__ float emb[DMODEL];
    for (int d = tid; d < DMODEL; d += 256) emb[d] = x[(size_t)sep * DMODEL + d];
    __syncthreads();

    const int o = blockIdx.x * 64 + (tid & 63);
    const int chunk = tid >> 6;
    float s = 0.f;
    const int d0 = chunk * 192;
    for (int d = d0; d < d0 + 192; ++d)
        s += emb[d] * w1[(size_t)d * 512 + o];
    __shared__ float part[4][64];
    part[chunk][tid & 63] = s;
    __syncthreads();
    if (chunk == 0) {
        float v = part[0][tid] + part[1][tid] + part[2][tid] + part[3][tid] + b1[o];
        z1[o] = fmaxf(v, 0.f);
    }
}

__global__ __launch_bounds__(256) void head2_kernel(const float* __restrict__ z1,
                                                    const float* __restrict__ w2,
                                                    const float* __restrict__ b2,
                                                    const float* __restrict__ w3,
                                                    const float* __restrict__ b3,
                                                    float* __restrict__ out) {
    const int tid = threadIdx.x;
    __shared__ float z1s[512];
    for (int i = tid; i < 512; i += 256) z1s[i] = z1[i];
    __syncthreads();
    float s = b2[tid];
    for (int d = 0; d < 512; ++d) s += z1s[d] * w2[(size_t)d * 256 + tid];
    float z2 = fmaxf(s, 0.f);
    __shared__ float fred[256];
    fred[tid] = z2 * w3[tid];
    __syncthreads();
    for (int s2 = 128; s2; s2 >>= 1) {
        if (tid < s2) fred[tid] += fred[tid + s2];
        __syncthreads();
    }
    if (tid == 0) out[0] = tanhf(fred[0] + b3[0]);
}

// ---------------- launch ----------------

extern "C" void kernel_launch(void* const* d_in, const int* in_sizes, int n_in,
                              void* d_out, int out_size, void* d_ws, size_t ws_size,
                              hipStream_t stream) {
    const int*   ids      = (const int*)d_in[0];
    const int*   amask    = (const int*)d_in[1];
    const float* word_emb = (const float*)d_in[2];
    const float* pos_emb  = (const float*)d_in[3];
    const float* emb_s    = (const float*)d_in[4];
    const float* emb_b    = (const float*)d_in[5];
    const float* Wq = (const float*)d_in[6];
    const float* bq = (const float*)d_in[7];
    const float* Wk = (const float*)d_in[8];
    const float* bk = (const float*)d_in[9];
    const float* Wv = (const float*)d_in[10];
    const float* bv = (const float*)d_in[11];
    const float* Wo = (const float*)d_in[12];
    const float* bo = (const float*)d_in[13];
    const float* l1s = (const float*)d_in[14];
    const float* l1b = (const float*)d_in[15];
    const float* W1 = (const float*)d_in[16];
    const float* b1 = (const float*)d_in[17];
    const float* W2 = (const float*)d_in[18];
    const float* b2 = (const float*)d_in[19];
    const float* l2s = (const float*)d_in[20];
    const float* l2b = (const float*)d_in[21];
    const float* h1w = (const float*)d_in[22];
    const float* h1b = (const float*)d_in[23];
    const float* h2w = (const float*)d_in[24];
    const float* h2b = (const float*)d_in[25];
    const float* h3w = (const float*)d_in[26];
    const float* h3b = (const float*)d_in[27];

    char* ws = (char*)d_ws;
    float* x          = (float*)(ws);                              // 12.58 MB
    float* t          = (float*)(ws + 12582912);                   // 12.58 MB
    unsigned short* xb   = (unsigned short*)(ws + 25165824);       // 6.29 MB
    unsigned short* qkv  = (unsigned short*)(ws + 31457280);       // 18.87 MB
    unsigned short* a    = (unsigned short*)(ws + 50331648);       // 6.29 MB
    unsigned short* hb   = (unsigned short*)(ws + 56623104);       // 25.17 MB
    unsigned short* WqkvT= (unsigned short*)(ws + 81788928);       // 3.54 MB
    unsigned short* WoT  = (unsigned short*)(ws + 85327872);       // 1.18 MB
    unsigned short* W1T  = (unsigned short*)(ws + 86507520);       // 4.72 MB
    unsigned short* W2T  = (unsigned short*)(ws + 91226112);       // 4.72 MB
    float* biascat       = (float*)(ws + 95944704);                // 0.11 MB
    float* z1ws          = (float*)(ws + 96055296);                // 2 KB

    bias_concat<<<NLAYER, 256, 0, stream>>>(bq, bk, bv, biascat);
    embed_ln_kernel<<<S_LEN, 256, 0, stream>>>(ids, word_emb, pos_emb, emb_s, emb_b, x, xb);

    const size_t dd = (size_t)DMODEL * DMODEL;
    const size_t df = (size_t)DMODEL * FFDIM;

    for (int l = 0; l < NLAYER; ++l) {
        transpose_all<<<6912, 256, 0, stream>>>(Wq + l * dd, Wk + l * dd, Wv + l * dd, Wo + l * dd,
                                                W1 + l * df, W2 + l * df,
                                                WqkvT, WqkvT + dd, WqkvT + 2 * dd, WoT, W1T, W2T);

        mfma_gemm<1, 128><<<dim3(32, 18), 256, 0, stream>>>(xb, WqkvT, biascat + (size_t)l * QKVN,
                                                            nullptr, qkv, S_LEN, QKVN, DMODEL);
        attn_mfma<<<dim3(S_LEN / 64, NHEAD), 256, 0, stream>>>(qkv, amask, a);

        mfma_gemm<0, 64><<<dim3(32, 12), 256, 0, stream>>>(a, WoT, bo + (size_t)l * DMODEL,
                                                           x, t, S_LEN, DMODEL, DMODEL);
        ln_kernel<<<S_LEN, 256, 0, stream>>>(t, l1s + (size_t)l * DMODEL, l1b + (size_t)l * DMODEL, x, xb);

        mfma_gemm<2, 128><<<dim3(32, 24), 256, 0, stream>>>(xb, W1T, b1 + (size_t)l * FFDIM,
                                                            nullptr, hb, S_LEN, FFDIM, DMODEL);
        mfma_gemm<0, 64><<<dim3(32, 12), 256, 0, stream>>>(hb, W2T, b2 + (size_t)l * DMODEL,
                                                           x, t, S_LEN, DMODEL, FFDIM);
        ln_kernel<<<S_LEN, 256, 0, stream>>>(t, l2s + (size_t)l * DMODEL, l2b + (size_t)l * DMODEL, x, xb);
    }

    head1_kernel<<<8, 256, 0, stream>>>(ids, x, h1w, h1b, z1ws);
    head2_kernel<<<1, 256, 0, stream>>>(z1ws, h2w, h2b, h3w, h3b, (float*)d_out);
}